// Round 1
// baseline (1456.743 us; speedup 1.0000x reference)
//
#include <hip/hip_runtime.h>

#define N_NODESC 20000
#define N_EDGESC 320000
#define HC 640
#define NGRAPH 500

__device__ __forceinline__ float wred_sum(float v){
  #pragma unroll
  for(int o=32;o;o>>=1) v += __shfl_xor(v,o,64);
  return v;
}
__device__ __forceinline__ float wred_max(float v){
  #pragma unroll
  for(int o=32;o;o>>=1) v = fmaxf(v,__shfl_xor(v,o,64));
  return v;
}
__device__ __forceinline__ float lrelu(float x){ return x>0.f? x:0.2f*x; }

// ---------------- graph preprocessing (layer-invariant) ----------------

__global__ void k_edge_stats(const float* __restrict__ eattr, const int* __restrict__ dst,
                             float* __restrict__ degf, float* __restrict__ lsum,
                             int* __restrict__ cnt){
  int i=blockIdx.x*blockDim.x+threadIdx.x;
  if(i>=N_EDGESC) return;
  int d=dst[i];
  atomicAdd(&degf[d],1.f);
  atomicAdd(&cnt[d],1);
  #pragma unroll
  for(int k=0;k<10;k++) atomicAdd(&lsum[d*10+k], eattr[i*10+k]);
}

__global__ void k_loop_div(float* __restrict__ lattr, const float* __restrict__ degf){
  int n=blockIdx.x*blockDim.x+threadIdx.x;
  if(n>=N_NODESC) return;
  float inv=1.f/fmaxf(degf[n],1.f);
  #pragma unroll
  for(int k=0;k<10;k++) lattr[n*10+k]*=inv;
}

// single-block exclusive scan of cnt[N] -> rptr, pos
__global__ void k_scan(const int* __restrict__ cnt, int* __restrict__ rptr, int* __restrict__ pos){
  __shared__ int ps[1024];
  int t=threadIdx.x;
  const int CH=20;                  // 1024*20 >= 20000
  int beg=t*CH, end=min(beg+CH, N_NODESC);
  int s=0;
  for(int i=beg;i<end;i++) s+=cnt[i];
  ps[t]=s; __syncthreads();
  for(int off=1;off<1024;off<<=1){
    int v=(t>=off)? ps[t-off]:0;
    __syncthreads();
    ps[t]+=v;
    __syncthreads();
  }
  int base=ps[t]-s;                 // exclusive prefix
  for(int i=beg;i<end;i++){ rptr[i]=base; pos[i]=base; base+=cnt[i]; }
}

__global__ void k_scatter(const int* __restrict__ dst, int* __restrict__ pos, int* __restrict__ eidx){
  int i=blockIdx.x*blockDim.x+threadIdx.x;
  if(i>=N_EDGESC) return;
  int j=atomicAdd(&pos[dst[i]],1);
  eidx[j]=i;
}

// ---------------- per-layer kernels ----------------

// v_e[k][h] = sum_c We[k, h*128+c] * a_edge[h*128+c]   (10x5)
__global__ void k_ve(const float* __restrict__ We, const float* __restrict__ aedge,
                     float* __restrict__ ve){
  int t=threadIdx.x;
  if(t>=50) return;
  int k=t/5, h=t%5;
  float s=0.f;
  for(int c=0;c<128;c++) s += We[k*HC + h*128 + c]*aedge[h*128+c];
  ve[k*5+h]=s;
}

// C[M][640] = A[M][K] @ B[K][640], f32 tiled
__global__ __launch_bounds__(256) void k_gemm(const float* __restrict__ A, const float* __restrict__ B,
                                              float* __restrict__ C, int M, int K){
  __shared__ float As[16][65];
  __shared__ float Bs[16][64];
  int tid=threadIdx.x;
  int tx=tid&15, ty=tid>>4;
  int row0=blockIdx.y*64, col0=blockIdx.x*64;
  float acc[4][4]={};
  for(int k0=0;k0<K;k0+=16){
    #pragma unroll
    for(int r=0;r<4;r++){
      int e=tid+256*r;
      int m=e>>4, kk=e&15;
      int row=row0+m, kg=k0+kk;
      As[kk][m] = (row<M && kg<K)? A[(long)row*K+kg] : 0.f;
      int kb=e>>6, c=e&63;
      int kg2=k0+kb;
      Bs[kb][c] = (kg2<K)? B[(long)kg2*HC + col0 + c] : 0.f;
    }
    __syncthreads();
    #pragma unroll
    for(int kk=0;kk<16;kk++){
      float a[4],b[4];
      #pragma unroll
      for(int i=0;i<4;i++) a[i]=As[kk][ty*4+i];
      #pragma unroll
      for(int j=0;j<4;j++) b[j]=Bs[kk][tx*4+j];
      #pragma unroll
      for(int i=0;i<4;i++)
        #pragma unroll
        for(int j=0;j<4;j++) acc[i][j]+=a[i]*b[j];
    }
    __syncthreads();
  }
  #pragma unroll
  for(int i=0;i<4;i++){
    int row=row0+ty*4+i;
    if(row<M){
      float4 v=make_float4(acc[i][0],acc[i][1],acc[i][2],acc[i][3]);
      *(float4*)&C[(long)row*HC + col0 + tx*4]=v;
    }
  }
}

// per-node: a_l, a_r (reductions of h*a_src / h*a_dst per head), and a_e_loop
__global__ __launch_bounds__(256) void k_nodeatt(const float* __restrict__ h,
    const float* __restrict__ asrc, const float* __restrict__ adst,
    const float* __restrict__ lattr, const float* __restrict__ ve,
    float* __restrict__ al, float* __restrict__ ar, float* __restrict__ ael){
  __shared__ float ves[50];
  int tid=threadIdx.x;
  if(tid<50) ves[tid]=ve[tid];
  __syncthreads();
  int lane=tid&63;
  int n=blockIdx.x*4+(tid>>6);
  if(n>=N_NODESC) return;
  float pl[5]={0,0,0,0,0}, pr[5]={0,0,0,0,0};
  #pragma unroll
  for(int k=0;k<10;k++){
    int c=lane+64*k;
    float hv=h[(long)n*HC+c];
    pl[k>>1]+=hv*asrc[c];
    pr[k>>1]+=hv*adst[c];
  }
  #pragma unroll
  for(int hh=0;hh<5;hh++){
    float sl=wred_sum(pl[hh]);
    float sr=wred_sum(pr[hh]);
    if(lane==0){ al[n*5+hh]=sl; ar[n*5+hh]=sr; }
  }
  if(lane<5){
    float s=0.f;
    #pragma unroll
    for(int k=0;k<10;k++) s+=lattr[n*10+k]*ves[k*5+lane];
    ael[n*5+lane]=s;
  }
}

// per-edge a_e for real edges
__global__ void k_ae(const float* __restrict__ eattr, const float* __restrict__ ve,
                     float* __restrict__ ae){
  __shared__ float ves[50];
  if(threadIdx.x<50) ves[threadIdx.x]=ve[threadIdx.x];
  __syncthreads();
  int i=blockIdx.x*blockDim.x+threadIdx.x;
  if(i>=N_EDGESC) return;
  float ev[10];
  #pragma unroll
  for(int k=0;k<10;k++) ev[k]=eattr[i*10+k];
  #pragma unroll
  for(int hh=0;hh<5;hh++){
    float s=0.f;
    #pragma unroll
    for(int k=0;k<10;k++) s+=ev[k]*ves[k*5+hh];
    ae[(long)i*5+hh]=s;
  }
}

// fused segment-softmax + weighted aggregation; one wave per node
template<bool RELU>
__global__ __launch_bounds__(256) void k_agg(const float* __restrict__ hf, const int* __restrict__ src,
    const int* __restrict__ rptr, const int* __restrict__ cnt, const int* __restrict__ eidx,
    const float* __restrict__ al, const float* __restrict__ ar, const float* __restrict__ ael,
    const float* __restrict__ ae, const float* __restrict__ bias, float* __restrict__ out){
  int tid=threadIdx.x, lane=tid&63;
  int n=blockIdx.x*4+(tid>>6);
  if(n>=N_NODESC) return;
  float arn[5], m[5], den[5], acc[10];
  #pragma unroll
  for(int hh=0;hh<5;hh++) arn[hh]=ar[n*5+hh];
  #pragma unroll
  for(int hh=0;hh<5;hh++){           // self-loop initializes the online softmax
    m[hh]=lrelu(al[n*5+hh]+arn[hh]+ael[n*5+hh]);
    den[hh]=1.f;
  }
  #pragma unroll
  for(int k=0;k<10;k++) acc[k]=hf[(long)n*HC+lane+64*k];   // p_selfloop = 1
  int beg=rptr[n], deg=cnt[n];
  for(int off0=0; off0<deg; off0+=64){
    int c=min(64,deg-off0);
    bool valid = lane<c;
    int s=0; float p[5];
    #pragma unroll
    for(int hh=0;hh<5;hh++) p[hh]=-1e30f;
    if(valid){
      int e=eidx[beg+off0+lane];
      s=src[e];
      #pragma unroll
      for(int hh=0;hh<5;hh++) p[hh]=lrelu(al[s*5+hh]+arn[hh]+ae[(long)e*5+hh]);
    }
    float sc[5];
    #pragma unroll
    for(int hh=0;hh<5;hh++){
      float cm=wred_max(p[hh]);
      float nm=fmaxf(m[hh],cm);
      sc[hh]=__expf(m[hh]-nm);
      den[hh]*=sc[hh];
      float pv = valid? __expf(p[hh]-nm) : 0.f;
      p[hh]=pv;
      den[hh]+=wred_sum(pv);
      m[hh]=nm;
    }
    #pragma unroll
    for(int k=0;k<10;k++) acc[k]*=sc[k>>1];
    for(int j=0;j<c;j++){
      int sj=__shfl(s,j,64);
      float pj[5];
      #pragma unroll
      for(int hh=0;hh<5;hh++) pj[hh]=__shfl(p[hh],j,64);
      const float* hr=&hf[(long)sj*HC];
      #pragma unroll
      for(int k=0;k<10;k++) acc[k]+=pj[k>>1]*hr[lane+64*k];
    }
  }
  #pragma unroll
  for(int k=0;k<10;k++){
    int ccol=lane+64*k;
    float v=acc[k]/(den[k>>1]+1e-16f)+bias[ccol];
    if(RELU) v=fmaxf(v,0.f);
    out[(long)n*HC+ccol]=v;
  }
}

// ---------------- pooling + head ----------------

__global__ __launch_bounds__(256) void k_pool(const float* __restrict__ h, const float* __restrict__ wlin,
    const int* __restrict__ batch, float* __restrict__ ysum, float* __restrict__ cntg){
  int tid=threadIdx.x, lane=tid&63;
  int n=blockIdx.x*4+(tid>>6);
  if(n>=N_NODESC) return;
  float s=0.f;
  #pragma unroll
  for(int k=0;k<10;k++){ int c=lane+64*k; s+=h[(long)n*HC+c]*wlin[c]; }
  s=wred_sum(s);
  if(lane==0){
    int g=batch[n];
    atomicAdd(&ysum[g],s);
    atomicAdd(&cntg[g],1.f);
  }
}

__global__ void k_final(const float* __restrict__ ysum, const float* __restrict__ cntg,
                        const float* __restrict__ blin, float* __restrict__ out){
  int g=blockIdx.x*blockDim.x+threadIdx.x;
  if(g>=NGRAPH) return;
  out[g]=ysum[g]/fmaxf(cntg[g],1.f)+blin[0];
}

// ---------------- launch ----------------

extern "C" void kernel_launch(void* const* d_in, const int* in_sizes, int n_in,
                              void* d_out, int out_size, void* d_ws, size_t ws_size,
                              hipStream_t stream){
  const float* x     = (const float*)d_in[0];
  const float* eattr = (const float*)d_in[1];
  const float* W[3]    ={(const float*)d_in[2],(const float*)d_in[8],(const float*)d_in[14]};
  const float* We[3]   ={(const float*)d_in[3],(const float*)d_in[9],(const float*)d_in[15]};
  const float* asrc[3] ={(const float*)d_in[4],(const float*)d_in[10],(const float*)d_in[16]};
  const float* adst[3] ={(const float*)d_in[5],(const float*)d_in[11],(const float*)d_in[17]};
  const float* aedge[3]={(const float*)d_in[6],(const float*)d_in[12],(const float*)d_in[18]};
  const float* bias[3] ={(const float*)d_in[7],(const float*)d_in[13],(const float*)d_in[19]};
  const float* Wlin  = (const float*)d_in[20];
  const float* blin  = (const float*)d_in[21];
  const int* eind    = (const int*)d_in[22];
  const int* srcp    = eind;
  const int* dstp    = eind + N_EDGESC;
  const int* batch   = (const int*)d_in[23];
  float* out = (float*)d_out;

  char* ws=(char*)d_ws;
  size_t o=0;
  auto alloc=[&](size_t bytes)->void*{ void* p=ws+o; o=(o+bytes+255)&~(size_t)255; return p; };
  float* bufA =(float*)alloc((size_t)N_NODESC*HC*4);
  float* bufB =(float*)alloc((size_t)N_NODESC*HC*4);
  float* al   =(float*)alloc((size_t)N_NODESC*5*4);
  float* ar   =(float*)alloc((size_t)N_NODESC*5*4);
  float* ael  =(float*)alloc((size_t)N_NODESC*5*4);
  float* ae   =(float*)alloc((size_t)N_EDGESC*5*4);
  float* lattr=(float*)alloc((size_t)N_NODESC*10*4);
  float* degf =(float*)alloc((size_t)N_NODESC*4);
  float* ve   =(float*)alloc(64*4);
  float* ysum =(float*)alloc(512*4);
  float* cntg =(float*)alloc(512*4);
  int* cntI   =(int*)alloc((size_t)N_NODESC*4);
  int* rptr   =(int*)alloc((size_t)N_NODESC*4);
  int* pos    =(int*)alloc((size_t)N_NODESC*4);
  int* eidx   =(int*)alloc((size_t)N_EDGESC*4);

  hipMemsetAsync(degf,0,(size_t)N_NODESC*4,stream);
  hipMemsetAsync(lattr,0,(size_t)N_NODESC*10*4,stream);
  hipMemsetAsync(cntI,0,(size_t)N_NODESC*4,stream);
  hipMemsetAsync(ysum,0,512*4,stream);
  hipMemsetAsync(cntg,0,512*4,stream);

  k_edge_stats<<<(N_EDGESC+255)/256,256,0,stream>>>(eattr,dstp,degf,lattr,cntI);
  k_loop_div<<<(N_NODESC+255)/256,256,0,stream>>>(lattr,degf);
  k_scan<<<1,1024,0,stream>>>(cntI,rptr,pos);
  k_scatter<<<(N_EDGESC+255)/256,256,0,stream>>>(dstp,pos,eidx);

  const float* in=x;
  float* hfeat=bufA;
  float* outb=bufB;
  int K=43;
  for(int L=0;L<3;L++){
    k_ve<<<1,64,0,stream>>>(We[L],aedge[L],ve);
    dim3 ggrid(HC/64,(N_NODESC+63)/64);
    k_gemm<<<ggrid,256,0,stream>>>(in,W[L],hfeat,N_NODESC,K);
    k_nodeatt<<<(N_NODESC+3)/4,256,0,stream>>>(hfeat,asrc[L],adst[L],lattr,ve,al,ar,ael);
    k_ae<<<(N_EDGESC+255)/256,256,0,stream>>>(eattr,ve,ae);
    if(L<2)
      k_agg<true ><<<(N_NODESC+3)/4,256,0,stream>>>(hfeat,srcp,rptr,cntI,eidx,al,ar,ael,ae,bias[L],outb);
    else
      k_agg<false><<<(N_NODESC+3)/4,256,0,stream>>>(hfeat,srcp,rptr,cntI,eidx,al,ar,ael,ae,bias[L],outb);
    // next layer: input = outb; hfeat reuses the other big buffer
    in=outb;
    hfeat=(L==0)? bufA : bufA;          // hfeat always bufA, outb always bufB? alternate below
    if(L==0){ hfeat=bufA; outb=bufB; }  // L1 wrote bufB
    // after L0: in=bufB, write hfeat into bufA (bufB preserved as input), agg -> bufB again?  No:
    // agg only reads hfeat + small arrays, so writing over the GEMM's input is safe.
    hfeat=bufA; outb=bufB;
    K=HC;
  }
  // final node features are in bufB
  k_pool<<<(N_NODESC+3)/4,256,0,stream>>>(bufB,Wlin,batch,ysum,cntg);
  k_final<<<2,256,0,stream>>>(ysum,cntg,blin,out);
}